// Round 9
// baseline (161.966 us; speedup 1.0000x reference)
//
#include <hip/hip_runtime.h>

// DetectionLoss: NB=3, C=20, S=7, D=35, B=8192 -> 401408 cells, ~112 MB read.
// R9 = R8 (byte-identical main path) + bw_probe INSTRUMENTATION kernel.
// Evidence so far: R3 (LDS-DMA), R4 (DMA dbuf), R8 (named-reg staging) all
// land at ~34us detloss = 3.3 TB/s actual; R5/R6/R7 also moved actual bytes
// at 2.9-3.3 TB/s despite wildly different instruction mixes. Hypothesis to
// settle: is ~3.3 TB/s the read wall for this workload, or do all my
// structures share a flaw? bw_probe = pure grid-stride float4 read of both
// tensors x2 (224 MB, passes 3/4 offset by half to defeat CSE), per-wave
// reduce, sink to unused d_ws region. If wall: probe ~68us, ranks in top-5
// with counters. If structure: probe ~36us, hidden, total +36.

#define NBOX 3
#define NCLS 20
#define SDIM 7
#define DCH  35
#define TILE_F4 560            // float4 per tensor per 64-cell tile
#define FLAT_F4 (2 * TILE_F4)  // 1120

__global__ __launch_bounds__(64, 2) void detloss_kernel(
    const float* __restrict__ out_g, const float* __restrict__ tgt_g,
    float* __restrict__ partials, int n_tiles, float inv_nB)
{
    __shared__ float4 s_buf[FLAT_F4];   // 17920 B: [0,560)=out, [560,1120)=tgt

    const int lane = threadIdx.x;       // one wave per block
    const int wid  = blockIdx.x;
    const int nwv  = gridDim.x;

    const float4* go;
    const float4* gt;
    float4 r0, r1, r2, r3, r4, r5, r6, r7, r8, r9,
           r10, r11, r12, r13, r14, r15, r16, r17;
    float lane_sum = 0.0f;

#define LOADJ(RJ, J) do {                                            \
        int k_ = (J) * 64 + lane;                                    \
        if (k_ > FLAT_F4 - 1) k_ = FLAT_F4 - 1;                      \
        RJ = (k_ < TILE_F4) ? go[k_] : gt[k_ - TILE_F4];             \
    } while (0)

#define STOREJ(RJ, J) do {                                           \
        const int k_ = (J) * 64 + lane;                              \
        s_buf[k_] = RJ;                                              \
    } while (0)

#define LOAD_TILE(T) do {                                            \
        go = (const float4*)out_g + (long long)(T) * TILE_F4;        \
        gt = (const float4*)tgt_g + (long long)(T) * TILE_F4;        \
        LOADJ(r0,0);  LOADJ(r1,1);  LOADJ(r2,2);  LOADJ(r3,3);       \
        LOADJ(r4,4);  LOADJ(r5,5);  LOADJ(r6,6);  LOADJ(r7,7);       \
        LOADJ(r8,8);  LOADJ(r9,9);  LOADJ(r10,10); LOADJ(r11,11);    \
        LOADJ(r12,12); LOADJ(r13,13); LOADJ(r14,14); LOADJ(r15,15);  \
        LOADJ(r16,16); LOADJ(r17,17);                                \
    } while (0)

#define STORE_TILE() do {                                            \
        STOREJ(r0,0);  STOREJ(r1,1);  STOREJ(r2,2);  STOREJ(r3,3);   \
        STOREJ(r4,4);  STOREJ(r5,5);  STOREJ(r6,6);  STOREJ(r7,7);   \
        STOREJ(r8,8);  STOREJ(r9,9);  STOREJ(r10,10); STOREJ(r11,11);\
        STOREJ(r12,12); STOREJ(r13,13); STOREJ(r14,14); STOREJ(r15,15);\
        STOREJ(r16,16);                                              \
        if (lane < 32) STOREJ(r17,17);  /* j=17 valid only for lanes<32 */ \
    } while (0)

    auto compute = [&]() {
        const float* sf = (const float*)s_buf;
        const float* o  = sf + lane * DCH;                 // packed 140B cells
        const float* g  = sf + 4 * TILE_F4 + lane * DCH;   // tgt section

        const float tx  = g[0] / 7.0f, ty = g[1] / 7.0f;
        const float thw = 0.5f * g[2], thh = 0.5f * g[3];
        const float tx1 = tx - thw, ty1 = ty - thh;
        const float tx2 = tx + thw, ty2 = ty + thh;
        const float a2  = (tx2 - tx1) * (ty2 - ty1);

        const float conf_t = g[4];
        const float obj    = (conf_t == 1.0f) ? 1.0f : 0.0f;
        const float noobj  = (conf_t == 0.0f) ? 1.0f : 0.0f;

        float biou = -__builtin_inff();  // strict > => first-index-wins (matches argmax)
        float conf_sq = 0.0f;
        float bo0 = 0.f, bo1 = 0.f, bo2 = 0.f, bo3 = 0.f, bo4 = 0.f;
        float bg0 = 0.f, bg1 = 0.f, bg2 = 0.f, bg3 = 0.f;

        #pragma unroll
        for (int i = 0; i < NBOX; ++i) {
            const float px  = o[5*i]   / 7.0f;
            const float py  = o[5*i+1] / 7.0f;
            const float phw = 0.5f * o[5*i+2];
            const float phh = 0.5f * o[5*i+3];
            const float px1 = px - phw, py1 = py - phh;
            const float px2 = px + phw, py2 = py + phh;

            const float ltx = fmaxf(px1, tx1), lty = fmaxf(py1, ty1);
            const float rbx = fminf(px2, tx2), rby = fminf(py2, ty2);
            const float w = fmaxf(rbx - ltx, 0.0f);
            const float h = fmaxf(rby - lty, 0.0f);
            const float inter = w * h;
            const float a1 = (px2 - px1) * (py2 - py1);
            const float iou = inter / (a1 + a2 - inter);

            const bool better = iou > biou;
            biou = better ? iou      : biou;
            bo0  = better ? o[5*i]   : bo0;
            bo1  = better ? o[5*i+1] : bo1;
            bo2  = better ? o[5*i+2] : bo2;
            bo3  = better ? o[5*i+3] : bo3;
            bo4  = better ? o[5*i+4] : bo4;
            bg0  = better ? g[5*i]   : bg0;
            bg1  = better ? g[5*i+1] : bg1;
            bg2  = better ? g[5*i+2] : bg2;
            bg3  = better ? g[5*i+3] : bg3;

            const float dc = o[5*i+4] - g[5*i+4];
            conf_sq += dc * dc;
        }

        float loss = 0.5f * noobj * conf_sq;

        const float dx = bo0 - bg0;
        const float dy = bo1 - bg1;
        const float xyl = dx*dx + dy*dy;
        const float dw = sqrtf(bo2) - sqrtf(bg2);
        const float dh = sqrtf(bo3) - sqrtf(bg3);
        const float whl = dw*dw + dh*dh;
        const float dcf = bo4 - biou;
        const float contain = dcf * dcf;

        float cls = 0.0f;
        #pragma unroll
        for (int c = 0; c < NCLS; ++c) {
            const float d = o[5*NBOX + c] - g[5*NBOX + c];
            cls += d * d;
        }

        lane_sum += loss + obj * (5.0f * (xyl + whl) + contain + cls);
    };

    // ---- software pipeline: load(t+1) in flight across compute(t), no barriers ----
    if (wid < n_tiles) {
        LOAD_TILE(wid);
        STORE_TILE();
        for (int nxt = wid + nwv; nxt < n_tiles; nxt += nwv) {
            LOAD_TILE(nxt);     // 18 loads in flight across compute below
            compute();          // reads LDS (in-order per wave vs writes after)
            STORE_TILE();
        }
        compute();
    }

    // ---- wave reduce -> one partial per wave ----
    float v = lane_sum * inv_nB;
    #pragma unroll
    for (int off = 32; off > 0; off >>= 1)
        v += __shfl_down(v, off);
    if (lane == 0) partials[wid] = v;
}

__global__ __launch_bounds__(1024) void reduce_kernel(
    const float* __restrict__ partials, float* __restrict__ out, int n)
{
    __shared__ float s[1024 / 64];
    float v = 0.0f;
    for (int i = threadIdx.x; i < n; i += 1024) v += partials[i];
    #pragma unroll
    for (int off = 32; off > 0; off >>= 1)
        v += __shfl_down(v, off);
    if ((threadIdx.x & 63) == 0) s[threadIdx.x >> 6] = v;
    __syncthreads();
    if (threadIdx.x == 0) {
        float t = 0.0f;
        #pragma unroll
        for (int w = 0; w < 1024 / 64; ++w) t += s[w];
        out[0] = t;
    }
}

// INSTRUMENTATION: pure-read bandwidth control, canonical copy-kernel shape.
// Reads both tensors twice (224 MB); passes 3/4 start offset by half to
// defeat CSE. Sink: per-wave sums to d_ws[8192..16384) (unused by main path).
__global__ __launch_bounds__(256) void bw_probe(
    const float4* __restrict__ a, const float4* __restrict__ b,
    float* __restrict__ sink, int nf4)
{
    const int gid    = blockIdx.x * 256 + threadIdx.x;
    const int stride = gridDim.x * 256;
    const int half   = nf4 / 2;

    float v = 0.0f;
    for (int i = gid; i < nf4; i += stride) { float4 x = a[i]; v += x.x + x.y + x.z + x.w; }
    for (int i = gid; i < nf4; i += stride) { float4 x = b[i]; v += x.x + x.y + x.z + x.w; }
    for (int i = gid; i < nf4; i += stride) {
        int j = i + half; if (j >= nf4) j -= nf4;
        float4 x = a[j]; v += x.x + x.y + x.z + x.w;
    }
    for (int i = gid; i < nf4; i += stride) {
        int j = i + half; if (j >= nf4) j -= nf4;
        float4 x = b[j]; v += x.x + x.y + x.z + x.w;
    }

    #pragma unroll
    for (int off = 32; off > 0; off >>= 1)
        v += __shfl_down(v, off);
    if ((threadIdx.x & 63) == 0)
        sink[(blockIdx.x * 4) + (threadIdx.x >> 6)] = v;
}

extern "C" void kernel_launch(void* const* d_in, const int* in_sizes, int n_in,
                              void* d_out, int out_size, void* d_ws, size_t ws_size,
                              hipStream_t stream) {
    const float* out_p = (const float*)d_in[0];
    const float* tgt_p = (const float*)d_in[1];
    float* res  = (float*)d_out;
    float* part = (float*)d_ws;
    float* sink = (float*)d_ws + 8192;               // beyond partials[0..2048)

    const int n_cells = in_sizes[0] / DCH;            // 401408
    const int nB = n_cells / (SDIM * SDIM);           // 8192
    const float inv_nB = 1.0f / (float)nB;
    const int n_tiles = n_cells / 64;                 // 6272 (exact)
    const int nf4 = in_sizes[0] / 4;                  // 3512320 float4 per tensor

    const int nblocks = 2048;                         // 8 single-wave blocks/CU (LDS-capped)
    hipLaunchKernelGGL(detloss_kernel, dim3(nblocks), dim3(64), 0, stream,
                       out_p, tgt_p, part, n_tiles, inv_nB);
    hipLaunchKernelGGL(reduce_kernel, dim3(1), dim3(1024), 0, stream,
                       part, res, nblocks);
    hipLaunchKernelGGL(bw_probe, dim3(2048), dim3(256), 0, stream,
                       (const float4*)out_p, (const float4*)tgt_p, sink, nf4);
}

// Round 10
// 133.844 us; speedup vs baseline: 1.2101x; 1.2101x over previous
//
#include <hip/hip_runtime.h>

// DetectionLoss: NB=3, C=20, S=7, D=35, B=8192 -> 401408 cells, ~112 MB read.
// R10: probe-shaped kernel. R9's bw_probe measured 6.7 TB/s pure-read in this
// harness (224MB in 33us, 32 waves/CU, no LDS) vs 3.3 TB/s for all my LDS
// staging structures (8 waves/CU) -> TLP was the limiter, LDS/wave the cap.
// This round: stage ONLY box channels (c<15, 7.7KB/wave, stride-15 banking),
// compute cls (c>=15) + noobj-conf (c in {4,9,14}) ELEMENTWISE in registers
// from the contiguous loads, weighted by the staged g[4] flag. 16 waves/CU
// via __launch_bounds__(128,4) (VGPR cap 128, est ~100 live). No barriers:
// 2 waves/block, each wave owns its tile + LDS region.

#define DCH  35
#define TILE_F4 560            // float4 per tensor per 64-cell tile

__global__ __launch_bounds__(128, 4) void detloss_kernel(
    const float* __restrict__ out_g, const float* __restrict__ tgt_g,
    float* __restrict__ partials, float inv_nB)
{
    __shared__ float s_o[2][960];   // [wave][cell*15+c], c<15 only
    __shared__ float s_g[2][960];

    const int lane = threadIdx.x & 63;
    const int wv   = threadIdx.x >> 6;
    const int tile = blockIdx.x * 2 + wv;      // grid sized exactly: no bounds check

    float* __restrict__ so = s_o[wv];
    float* __restrict__ sg = s_g[wv];

    const float4* go = (const float4*)out_g + (long long)tile * TILE_F4;
    const float4* gt = (const float4*)tgt_g + (long long)tile * TILE_F4;

    float4 o0,o1,o2,o3,o4,o5,o6,o7,o8;
    float4 g0,g1,g2,g3,g4,g5,g6,g7,g8;
    float ew_acc = 0.0f;

    // ---- 18 interleaved contiguous dwordx4 loads (copy-kernel shape) ----
#define ISSUE(J, OJ, GJ) do {                                   \
        const int k_ = (J)*64 + lane;                           \
        if ((J) < 8 || lane < 48) { OJ = go[k_]; GJ = gt[k_]; } \
    } while (0)

    ISSUE(0,o0,g0); ISSUE(1,o1,g1); ISSUE(2,o2,g2); ISSUE(3,o3,g3);
    ISSUE(4,o4,g4); ISSUE(5,o5,g5); ISSUE(6,o6,g6); ISSUE(7,o7,g7);
    ISSUE(8,o8,g8);

    // ---- phase A: scatter box channels (c<15) to LDS; square diffs into OJ ----
#define SCAT1(OV, GV) do {                                      \
        if (c_ < 15u) { unsigned a_ = cell_*15u + c_;           \
            so[a_] = (OV); sg[a_] = (GV); }                     \
        c_++; if (c_ == 35u) { c_ = 0u; cell_++; }              \
    } while (0)

#define SCATTER(J, OJ, GJ) do {                                 \
        if ((J) < 8 || lane < 48) {                             \
            unsigned e_ = 4u*(unsigned)((J)*64 + lane);         \
            unsigned cell_ = e_ / 35u;                          \
            unsigned c_ = e_ - cell_*35u;                       \
            SCAT1(OJ.x, GJ.x); SCAT1(OJ.y, GJ.y);               \
            SCAT1(OJ.z, GJ.z); SCAT1(OJ.w, GJ.w);               \
            OJ.x -= GJ.x; OJ.x *= OJ.x;                         \
            OJ.y -= GJ.y; OJ.y *= OJ.y;                         \
            OJ.z -= GJ.z; OJ.z *= OJ.z;                         \
            OJ.w -= GJ.w; OJ.w *= OJ.w;                         \
        }                                                       \
    } while (0)

    SCATTER(0,o0,g0); SCATTER(1,o1,g1); SCATTER(2,o2,g2); SCATTER(3,o3,g3);
    SCATTER(4,o4,g4); SCATTER(5,o5,g5); SCATTER(6,o6,g6); SCATTER(7,o7,g7);
    SCATTER(8,o8,g8);

    // ---- phase B: elementwise weighted accumulation (cls + noobj-conf) ----
    // w(c) = obj if c>=15 ; 0.5*noobj if c in {4,9,14} ; else 0
#define WSEL(C, OBJ, NO) ((C) >= 15u ? (OBJ) : (((C)==4u || (C)==9u || (C)==14u) ? (NO) : 0.0f))
#define ACC1(D2) do {                                           \
        ew_acc += WSEL(c_, objc_, noc_) * (D2);                 \
        c_++; if (c_ == 35u) { c_ = 0u; objc_ = obj1_; noc_ = no1_; } \
    } while (0)

#define ACCUM(J, OJ) do {                                       \
        if ((J) < 8 || lane < 48) {                             \
            unsigned e_ = 4u*(unsigned)((J)*64 + lane);         \
            unsigned cell_ = e_ / 35u;                          \
            unsigned c_ = e_ - cell_*35u;                       \
            const float f0_ = sg[cell_*15u + 4u];               \
            const float f1_ = (c_ >= 32u) ? sg[(cell_+1u)*15u + 4u] : f0_; \
            const float obj0_ = (f0_ == 1.0f) ? 1.0f : 0.0f;    \
            const float no0_  = (f0_ == 0.0f) ? 0.5f : 0.0f;    \
            const float obj1_ = (f1_ == 1.0f) ? 1.0f : 0.0f;    \
            const float no1_  = (f1_ == 0.0f) ? 0.5f : 0.0f;    \
            float objc_ = obj0_, noc_ = no0_;                   \
            ACC1(OJ.x); ACC1(OJ.y); ACC1(OJ.z); ACC1(OJ.w);     \
        }                                                       \
    } while (0)

    ACCUM(0,o0); ACCUM(1,o1); ACCUM(2,o2); ACCUM(3,o3);
    ACCUM(4,o4); ACCUM(5,o5); ACCUM(6,o6); ACCUM(7,o7);
    ACCUM(8,o8);

    // ---- coupled per-cell part: lane = cell, stride-15 LDS reads (conflict-free) ----
    const float* oc = so + lane * 15;
    const float* gc = sg + lane * 15;

    const float tx  = gc[0] / 7.0f, ty = gc[1] / 7.0f;
    const float thw = 0.5f * gc[2], thh = 0.5f * gc[3];
    const float tx1 = tx - thw, ty1 = ty - thh;
    const float tx2 = tx + thw, ty2 = ty + thh;
    const float a2  = (tx2 - tx1) * (ty2 - ty1);

    const float conf_t = gc[4];
    const float obj    = (conf_t == 1.0f) ? 1.0f : 0.0f;

    float biou = -__builtin_inff();   // strict > => first-index-wins (matches argmax)
    float bo0 = 0.f, bo1 = 0.f, bo2 = 0.f, bo3 = 0.f, bo4 = 0.f;
    float bg0 = 0.f, bg1 = 0.f, bg2 = 0.f, bg3 = 0.f;

    #pragma unroll
    for (int i = 0; i < 3; ++i) {
        const float ox = oc[5*i], oy = oc[5*i+1], ow = oc[5*i+2], oh = oc[5*i+3];
        const float px  = ox / 7.0f;
        const float py  = oy / 7.0f;
        const float phw = 0.5f * ow;
        const float phh = 0.5f * oh;
        const float px1 = px - phw, py1 = py - phh;
        const float px2 = px + phw, py2 = py + phh;

        const float ltx = fmaxf(px1, tx1), lty = fmaxf(py1, ty1);
        const float rbx = fminf(px2, tx2), rby = fminf(py2, ty2);
        const float w = fmaxf(rbx - ltx, 0.0f);
        const float h = fmaxf(rby - lty, 0.0f);
        const float inter = w * h;
        const float a1 = (px2 - px1) * (py2 - py1);
        const float iou = inter / (a1 + a2 - inter);

        const bool better = iou > biou;
        biou = better ? iou        : biou;
        bo0  = better ? ox         : bo0;
        bo1  = better ? oy         : bo1;
        bo2  = better ? ow         : bo2;
        bo3  = better ? oh         : bo3;
        bo4  = better ? oc[5*i+4]  : bo4;
        bg0  = better ? gc[5*i]    : bg0;
        bg1  = better ? gc[5*i+1]  : bg1;
        bg2  = better ? gc[5*i+2]  : bg2;
        bg3  = better ? gc[5*i+3]  : bg3;
    }

    const float dx = bo0 - bg0;
    const float dy = bo1 - bg1;
    const float xyl = dx*dx + dy*dy;
    const float dw = sqrtf(bo2) - sqrtf(bg2);
    const float dh = sqrtf(bo3) - sqrtf(bg3);
    const float whl = dw*dw + dh*dh;
    const float dcf = bo4 - biou;
    const float contain = dcf * dcf;

    float v = (ew_acc + obj * (5.0f * (xyl + whl) + contain)) * inv_nB;

    // ---- wave reduce -> one partial per wave(tile) ----
    #pragma unroll
    for (int off = 32; off > 0; off >>= 1)
        v += __shfl_down(v, off);
    if (lane == 0) partials[tile] = v;
}

__global__ __launch_bounds__(1024) void reduce_kernel(
    const float* __restrict__ partials, float* __restrict__ out, int n)
{
    __shared__ float s[1024 / 64];
    float v = 0.0f;
    for (int i = threadIdx.x; i < n; i += 1024) v += partials[i];
    #pragma unroll
    for (int off = 32; off > 0; off >>= 1)
        v += __shfl_down(v, off);
    if ((threadIdx.x & 63) == 0) s[threadIdx.x >> 6] = v;
    __syncthreads();
    if (threadIdx.x == 0) {
        float t = 0.0f;
        #pragma unroll
        for (int w = 0; w < 1024 / 64; ++w) t += s[w];
        out[0] = t;
    }
}

extern "C" void kernel_launch(void* const* d_in, const int* in_sizes, int n_in,
                              void* d_out, int out_size, void* d_ws, size_t ws_size,
                              hipStream_t stream) {
    const float* out_p = (const float*)d_in[0];
    const float* tgt_p = (const float*)d_in[1];
    float* res  = (float*)d_out;
    float* part = (float*)d_ws;

    const int n_cells = in_sizes[0] / DCH;            // 401408
    const int nB = n_cells / 49;                      // 8192
    const float inv_nB = 1.0f / (float)nB;
    const int n_tiles = n_cells / 64;                 // 6272 (exact)
    const int blocks  = n_tiles / 2;                  // 3136, 2 waves(tiles)/block

    hipLaunchKernelGGL(detloss_kernel, dim3(blocks), dim3(128), 0, stream,
                       out_p, tgt_p, part, inv_nB);
    hipLaunchKernelGGL(reduce_kernel, dim3(1), dim3(1024), 0, stream,
                       part, res, n_tiles);
}

// Round 11
// 129.752 us; speedup vs baseline: 1.2483x; 1.0315x over previous
//
#include <hip/hip_runtime.h>

// DetectionLoss: NB=3, C=20, S=7, D=35, B=8192 -> 401408 cells, ~112 MB read.
// R11 = R8's lean structure at 2x TLP. Evidence: probe (32 waves/CU, lean)
// = 6.7 TB/s; R8 (8 waves/CU, lean) = 3.3; R10 (9 waves, VALU-bloated) =
// 2.7. Full-channel staging costs 280 B/cell -> 64-cell tiles cap at ~9
// waves/CU. 32-cell tiles (8.96 KB/wave) + __launch_bounds__(64,4) -> 16
// blocks(waves)/CU. Code shape unchanged from R8: contiguous dwordx4 loads
// into 9 NAMED float4 regs (no array -> no scratch), trivial LDS stores,
// per-cell compute from LDS (lanes 0..31), persistent pipeline
// load(t+1)/compute(t)/store(t+1), zero barriers.

#define DCH  35
#define TILE_CELLS 32
#define TILE_F4 280            // float4 per tensor per 32-cell tile
#define FLAT_F4 (2 * TILE_F4)  // 560 = 8.75 waves of float4

__global__ __launch_bounds__(64, 4) void detloss_kernel(
    const float* __restrict__ out_g, const float* __restrict__ tgt_g,
    float* __restrict__ partials, int n_tiles, float inv_nB)
{
    __shared__ float4 s_buf[FLAT_F4];   // 8960 B: [0,280)=out, [280,560)=tgt

    const int lane = threadIdx.x;       // one wave per block
    const int wid  = blockIdx.x;
    const int nwv  = gridDim.x;

    const float4* go;
    const float4* gt;
    float4 r0, r1, r2, r3, r4, r5, r6, r7, r8;
    float lane_sum = 0.0f;

#define LOADJ(RJ, J) do {                                            \
        int k_ = (J) * 64 + lane;                                    \
        if (k_ > FLAT_F4 - 1) k_ = FLAT_F4 - 1;                      \
        RJ = (k_ < TILE_F4) ? go[k_] : gt[k_ - TILE_F4];             \
    } while (0)

#define STOREJ(RJ, J) do {                                           \
        const int k_ = (J) * 64 + lane;                              \
        s_buf[k_] = RJ;                                              \
    } while (0)

#define LOAD_TILE(T) do {                                            \
        go = (const float4*)out_g + (long long)(T) * TILE_F4;        \
        gt = (const float4*)tgt_g + (long long)(T) * TILE_F4;        \
        LOADJ(r0,0); LOADJ(r1,1); LOADJ(r2,2); LOADJ(r3,3);          \
        LOADJ(r4,4); LOADJ(r5,5); LOADJ(r6,6); LOADJ(r7,7);          \
        LOADJ(r8,8);                                                 \
    } while (0)

#define STORE_TILE() do {                                            \
        STOREJ(r0,0); STOREJ(r1,1); STOREJ(r2,2); STOREJ(r3,3);      \
        STOREJ(r4,4); STOREJ(r5,5); STOREJ(r6,6); STOREJ(r7,7);      \
        if (lane < 48) STOREJ(r8,8);  /* j=8 valid lanes<48 */       \
    } while (0)

    auto compute = [&]() {
        if (lane >= TILE_CELLS) return;                // lanes 32..63 idle here
        const float* sf = (const float*)s_buf;
        const float* o  = sf + lane * DCH;             // packed 140B cells
        const float* g  = sf + 4 * TILE_F4 + lane * DCH;

        const float tx  = g[0] / 7.0f, ty = g[1] / 7.0f;
        const float thw = 0.5f * g[2], thh = 0.5f * g[3];
        const float tx1 = tx - thw, ty1 = ty - thh;
        const float tx2 = tx + thw, ty2 = ty + thh;
        const float a2  = (tx2 - tx1) * (ty2 - ty1);

        const float conf_t = g[4];
        const float obj    = (conf_t == 1.0f) ? 1.0f : 0.0f;
        const float noobj  = (conf_t == 0.0f) ? 1.0f : 0.0f;

        float biou = -__builtin_inff();  // strict > => first-index-wins (matches argmax)
        float conf_sq = 0.0f;
        float bo0 = 0.f, bo1 = 0.f, bo2 = 0.f, bo3 = 0.f, bo4 = 0.f;
        float bg0 = 0.f, bg1 = 0.f, bg2 = 0.f, bg3 = 0.f;

        #pragma unroll
        for (int i = 0; i < 3; ++i) {
            const float px  = o[5*i]   / 7.0f;
            const float py  = o[5*i+1] / 7.0f;
            const float phw = 0.5f * o[5*i+2];
            const float phh = 0.5f * o[5*i+3];
            const float px1 = px - phw, py1 = py - phh;
            const float px2 = px + phw, py2 = py + phh;

            const float ltx = fmaxf(px1, tx1), lty = fmaxf(py1, ty1);
            const float rbx = fminf(px2, tx2), rby = fminf(py2, ty2);
            const float w = fmaxf(rbx - ltx, 0.0f);
            const float h = fmaxf(rby - lty, 0.0f);
            const float inter = w * h;
            const float a1 = (px2 - px1) * (py2 - py1);
            const float iou = inter / (a1 + a2 - inter);

            const bool better = iou > biou;
            biou = better ? iou      : biou;
            bo0  = better ? o[5*i]   : bo0;
            bo1  = better ? o[5*i+1] : bo1;
            bo2  = better ? o[5*i+2] : bo2;
            bo3  = better ? o[5*i+3] : bo3;
            bo4  = better ? o[5*i+4] : bo4;
            bg0  = better ? g[5*i]   : bg0;
            bg1  = better ? g[5*i+1] : bg1;
            bg2  = better ? g[5*i+2] : bg2;
            bg3  = better ? g[5*i+3] : bg3;

            const float dc = o[5*i+4] - g[5*i+4];
            conf_sq += dc * dc;
        }

        float loss = 0.5f * noobj * conf_sq;

        const float dx = bo0 - bg0;
        const float dy = bo1 - bg1;
        const float xyl = dx*dx + dy*dy;
        const float dw = sqrtf(bo2) - sqrtf(bg2);
        const float dh = sqrtf(bo3) - sqrtf(bg3);
        const float whl = dw*dw + dh*dh;
        const float dcf = bo4 - biou;
        const float contain = dcf * dcf;

        float cls = 0.0f;
        #pragma unroll
        for (int c = 0; c < 20; ++c) {
            const float d = o[15 + c] - g[15 + c];
            cls += d * d;
        }

        lane_sum += loss + obj * (5.0f * (xyl + whl) + contain + cls);
    };

    // ---- software pipeline: load(t+1) in flight across compute(t), no barriers ----
    if (wid < n_tiles) {
        LOAD_TILE(wid);
        STORE_TILE();
        for (int nxt = wid + nwv; nxt < n_tiles; nxt += nwv) {
            LOAD_TILE(nxt);     // 9 loads in flight across compute below
            compute();          // reads LDS (in-order per wave vs writes after)
            STORE_TILE();
        }
        compute();
    }

    // ---- wave reduce -> one partial per wave ----
    float v = lane_sum * inv_nB;    // lanes>=32 carry 0
    #pragma unroll
    for (int off = 32; off > 0; off >>= 1)
        v += __shfl_down(v, off);
    if (lane == 0) partials[wid] = v;
}

__global__ __launch_bounds__(1024) void reduce_kernel(
    const float* __restrict__ partials, float* __restrict__ out, int n)
{
    __shared__ float s[1024 / 64];
    float v = 0.0f;
    for (int i = threadIdx.x; i < n; i += 1024) v += partials[i];
    #pragma unroll
    for (int off = 32; off > 0; off >>= 1)
        v += __shfl_down(v, off);
    if ((threadIdx.x & 63) == 0) s[threadIdx.x >> 6] = v;
    __syncthreads();
    if (threadIdx.x == 0) {
        float t = 0.0f;
        #pragma unroll
        for (int w = 0; w < 1024 / 64; ++w) t += s[w];
        out[0] = t;
    }
}

extern "C" void kernel_launch(void* const* d_in, const int* in_sizes, int n_in,
                              void* d_out, int out_size, void* d_ws, size_t ws_size,
                              hipStream_t stream) {
    const float* out_p = (const float*)d_in[0];
    const float* tgt_p = (const float*)d_in[1];
    float* res  = (float*)d_out;
    float* part = (float*)d_ws;

    const int n_cells = in_sizes[0] / DCH;            // 401408
    const int nB = n_cells / 49;                      // 8192
    const float inv_nB = 1.0f / (float)nB;
    const int n_tiles = n_cells / TILE_CELLS;         // 12544 (exact)

    const int nblocks = 4096;                         // 16 single-wave blocks/CU
    hipLaunchKernelGGL(detloss_kernel, dim3(nblocks), dim3(64), 0, stream,
                       out_p, tgt_p, part, n_tiles, inv_nB);
    hipLaunchKernelGGL(reduce_kernel, dim3(1), dim3(1024), 0, stream,
                       part, res, nblocks);
}